// Round 1
// baseline (384.410 us; speedup 1.0000x reference)
//
#include <hip/hip_runtime.h>

#define OUTSZ 7
#define SR 2
#define SS (OUTSZ*SR)        // 14 sample rows/cols
#define NS (SS*SS)           // 196 samples per box
#define C_BAND 256           // channels per band
#define H_BAND 100
#define W_FULL 200
#define PLANE (2*H_BAND*W_FULL)   // 40000 elems per full channel plane
#define CCHUNK 64            // channels per block
#define NCHUNK (C_BAND/CCHUNK)    // 4

__global__ __launch_bounds__(256) void roi_align_kernel(
    const float* __restrict__ feat,   // [4,256,200,200]
    const float* __restrict__ boxes,  // [512,5]
    float* __restrict__ out)          // [512,512,7,7]
{
    // SoA layout: lane-adjacent s -> stride-1 LDS banks (conflict-free)
    __shared__ int   s_idx[4][NS];
    __shared__ float s_w[4][NS];

    const int b     = blockIdx.x;
    const int chunk = b & (NCHUNK - 1);
    const int band  = (b >> 2) & 1;
    const int k     = b >> 3;

    const int tid = threadIdx.x;

    // Box params: k is block-uniform -> these become scalar loads
    const float bxf = boxes[k*5 + 0];
    const float x1  = boxes[k*5 + 1];
    const float y1  = boxes[k*5 + 2];
    const float x2  = boxes[k*5 + 3];
    const float y2  = boxes[k*5 + 4];
    const int   n   = (int)bxf;

    const float roi_w = fmaxf(x2 - x1, 1.0f);
    const float roi_h = fmaxf(y2 - y1, 1.0f);
    const float bin_w = roi_w / 7.0f;   // exact div to match reference rounding
    const float bin_h = roi_h / 7.0f;

    if (tid < NS) {
        const int sy = tid / SS;
        const int sx = tid - sy * SS;
        const int ph = sy >> 1, iy = sy & 1;
        const int pw = sx >> 1, ix = sx & 1;
        // off = (i + 0.5)/2 -> 0.25 / 0.75, exact
        float y = y1 + ((float)ph + ((float)iy + 0.5f) * 0.5f) * bin_h;
        float x = x1 + ((float)pw + ((float)ix + 0.5f) * 0.5f) * bin_w;
        const bool valid = (y >= -1.0f) && (y <= (float)H_BAND) &&
                           (x >= -1.0f) && (x <= (float)W_FULL);
        y = fminf(fmaxf(y, 0.0f), (float)(H_BAND - 1));
        x = fminf(fmaxf(x, 0.0f), (float)(W_FULL - 1));
        const int y_lo = (int)floorf(y);
        const int x_lo = (int)floorf(x);
        const int y_hi = min(y_lo + 1, H_BAND - 1);
        const int x_hi = min(x_lo + 1, W_FULL - 1);
        const float ly = y - (float)y_lo;
        const float lx = x - (float)x_lo;
        const float hy = 1.0f - ly, hx = 1.0f - lx;
        const float vs = valid ? 1.0f : 0.0f;
        s_idx[0][tid] = y_lo * W_FULL + x_lo;
        s_idx[1][tid] = y_lo * W_FULL + x_hi;
        s_idx[2][tid] = y_hi * W_FULL + x_lo;
        s_idx[3][tid] = y_hi * W_FULL + x_hi;
        s_w[0][tid] = hy * hx * vs;
        s_w[1][tid] = hy * lx * vs;
        s_w[2][tid] = ly * hx * vs;
        s_w[3][tid] = ly * lx * vs;
    }
    __syncthreads();

    const int c0 = chunk * CCHUNK;
    // address = (n*256 + c)*40000 + band*20000 + local
    const float* fbase = feat + (size_t)(n * C_BAND + c0) * PLANE
                              + (size_t)band * (H_BAND * W_FULL);
    float* obase = out + ((size_t)k * (2*C_BAND) + (size_t)band * C_BAND + c0)
                       * (OUTSZ * OUTSZ);

    const int NOUT = CCHUNK * OUTSZ * OUTSZ;   // 3136
    for (int o = tid; o < NOUT; o += 256) {
        const int c   = o / 49;
        const int bin = o - c * 49;
        const int ph  = bin / 7;
        const int pw  = bin - ph * 7;
        const float* fc = fbase + (size_t)c * PLANE;
        const int s00 = (ph * 2) * SS + pw * 2;
        float acc = 0.0f;
        #pragma unroll
        for (int iy = 0; iy < 2; ++iy) {
            #pragma unroll
            for (int ix = 0; ix < 2; ++ix) {
                const int s = s00 + iy * SS + ix;
                acc += s_w[0][s] * fc[s_idx[0][s]];
                acc += s_w[1][s] * fc[s_idx[1][s]];
                acc += s_w[2][s] * fc[s_idx[2][s]];
                acc += s_w[3][s] * fc[s_idx[3][s]];
            }
        }
        obase[o] = acc * 0.25f;   // store is coalesced: o is linear per thread
    }
}

extern "C" void kernel_launch(void* const* d_in, const int* in_sizes, int n_in,
                              void* d_out, int out_size, void* d_ws, size_t ws_size,
                              hipStream_t stream) {
    const float* feat  = (const float*)d_in[0];   // [4,256,200,200] f32
    const float* boxes = (const float*)d_in[1];   // [512,5] f32
    float* out = (float*)d_out;                   // [512,512,7,7] f32

    const int nblocks = 512 * 2 * NCHUNK;         // 4096
    roi_align_kernel<<<nblocks, 256, 0, stream>>>(feat, boxes, out);
}

// Round 2
// 325.251 us; speedup vs baseline: 1.1819x; 1.1819x over previous
//
#include <hip/hip_runtime.h>

#define OUTSZ 7
#define SR 2
#define SS (OUTSZ*SR)        // 14 sample rows/cols
#define NS (SS*SS)           // 196 samples per box
#define C_BAND 256
#define H_BAND 100
#define W_FULL 200
#define PLANE (2*H_BAND*W_FULL)   // 40000 elems per full channel plane
#define CCHUNK 64
#define NCHUNK (C_BAND/CCHUNK)    // 4
#define NBOX 512

// Pre-pass: sort box indices by (batch, y1) so the main kernel's per-XCD
// box stream walks the image top-to-bottom per batch -> sliding ~2MB L2
// working set instead of random 20MB thrash.
__global__ __launch_bounds__(256) void sort_boxes_kernel(
    const float* __restrict__ boxes, int* __restrict__ perm)
{
    __shared__ int keys[NBOX];
    __shared__ int vals[NBOX];
    const int tid = threadIdx.x;
    for (int i = tid; i < NBOX; i += 256) {
        const int n = (int)boxes[i*5 + 0];
        const int y = (int)boxes[i*5 + 2];
        keys[i] = n * 256 + y;
        vals[i] = i;
    }
    __syncthreads();
    for (int size = 2; size <= NBOX; size <<= 1) {
        for (int stride = size >> 1; stride > 0; stride >>= 1) {
            const int i = (tid / stride) * (stride * 2) + (tid % stride);
            const int j = i + stride;
            const bool up = ((i & size) == 0);
            const int ki = keys[i], kj = keys[j];
            if ((ki > kj) == up) {
                keys[i] = kj; keys[j] = ki;
                const int v = vals[i]; vals[i] = vals[j]; vals[j] = v;
            }
            __syncthreads();
        }
    }
    for (int i = tid; i < NBOX; i += 256) perm[i] = vals[i];
}

__global__ __launch_bounds__(256) void roi_align_kernel(
    const float* __restrict__ feat,   // [4,256,200,200]
    const float* __restrict__ boxes,  // [512,5]
    const int*   __restrict__ perm,   // [512] sorted box order
    float* __restrict__ out)          // [512,512,7,7]
{
    // Per-sample tables: row-pair base indices + 4 folded weights.
    __shared__ int    s_i0[NS];
    __shared__ int    s_i1[NS];
    __shared__ float4 s_w[NS];

    const int b     = blockIdx.x;
    const int j     = b & 7;          // (band*4+chunk) -> fixed XCD (b%8 heuristic)
    const int chunk = j & 3;
    const int band  = j >> 2;
    const int k     = perm[b >> 3];   // sorted box order within each XCD stream

    const int tid = threadIdx.x;

    const float bxf = boxes[k*5 + 0];
    const float x1  = boxes[k*5 + 1];
    const float y1  = boxes[k*5 + 2];
    const float x2  = boxes[k*5 + 3];
    const float y2  = boxes[k*5 + 4];
    const int   n   = (int)bxf;

    const float roi_w = fmaxf(x2 - x1, 1.0f);
    const float roi_h = fmaxf(y2 - y1, 1.0f);
    const float bin_w = roi_w / 7.0f;
    const float bin_h = roi_h / 7.0f;

    if (tid < NS) {
        const int sy = tid / SS;
        const int sx = tid - sy * SS;
        const int ph = sy >> 1, iy = sy & 1;
        const int pw = sx >> 1, ix = sx & 1;
        float y = y1 + ((float)ph + ((float)iy + 0.5f) * 0.5f) * bin_h;
        float x = x1 + ((float)pw + ((float)ix + 0.5f) * 0.5f) * bin_w;
        const bool valid = (y >= -1.0f) && (y <= (float)H_BAND) &&
                           (x >= -1.0f) && (x <= (float)W_FULL);
        y = fminf(fmaxf(y, 0.0f), (float)(H_BAND - 1));
        x = fminf(fmaxf(x, 0.0f), (float)(W_FULL - 1));
        const int y_lo = (int)floorf(y);
        const int x_lo = (int)floorf(x);
        const int y_hi = min(y_lo + 1, H_BAND - 1);
        const float ly = y - (float)y_lo;
        const float lx = x - (float)x_lo;
        const float hy = 1.0f - ly, hx = 1.0f - lx;
        // Pair the x_lo/x_hi corners into one float2 at xb=min(x_lo,W-2).
        // If x_lo==W-1 (clamped; lx==0 there), shift all weight onto v[1].
        const int xb = min(x_lo, W_FULL - 2);
        float w0, w1;
        if (x_lo == xb) { w0 = hx; w1 = lx; }
        else            { w0 = 0.0f; w1 = hx + lx; }   // == hx, lx==0
        const float vs = valid ? 1.0f : 0.0f;
        s_i0[tid] = y_lo * W_FULL + xb;
        s_i1[tid] = y_hi * W_FULL + xb;
        s_w[tid] = make_float4(hy * w0 * vs, hy * w1 * vs,
                               ly * w0 * vs, ly * w1 * vs);
    }
    __syncthreads();

    const int c0 = chunk * CCHUNK;
    const float* fbase = feat + (size_t)(n * C_BAND + c0) * PLANE
                              + (size_t)band * (H_BAND * W_FULL);
    float* obase = out + ((size_t)k * (2*C_BAND) + (size_t)band * C_BAND + c0)
                       * (OUTSZ * OUTSZ);

    const int NOUT = CCHUNK * OUTSZ * OUTSZ;   // 3136
    for (int o = tid; o < NOUT; o += 256) {
        const int c   = o / 49;
        const int bin = o - c * 49;
        const int ph  = bin / 7;
        const int pw  = bin - ph * 7;
        const float* fc = fbase + (size_t)c * PLANE;
        const int s00 = (ph * 2) * SS + pw * 2;
        float acc = 0.0f;
        #pragma unroll
        for (int iy = 0; iy < 2; ++iy) {
            #pragma unroll
            for (int ix = 0; ix < 2; ++ix) {
                const int s = s00 + iy * SS + ix;
                const float4 w = s_w[s];
                const float2 a = *(const float2*)(fc + s_i0[s]);
                const float2 d = *(const float2*)(fc + s_i1[s]);
                acc += w.x * a.x + w.y * a.y + w.z * d.x + w.w * d.y;
            }
        }
        obase[o] = acc * 0.25f;
    }
}

extern "C" void kernel_launch(void* const* d_in, const int* in_sizes, int n_in,
                              void* d_out, int out_size, void* d_ws, size_t ws_size,
                              hipStream_t stream) {
    const float* feat  = (const float*)d_in[0];   // [4,256,200,200] f32
    const float* boxes = (const float*)d_in[1];   // [512,5] f32
    float* out = (float*)d_out;                   // [512,512,7,7] f32
    int* perm = (int*)d_ws;                       // 512 ints

    sort_boxes_kernel<<<1, 256, 0, stream>>>(boxes, perm);
    const int nblocks = NBOX * 2 * NCHUNK;        // 4096
    roi_align_kernel<<<nblocks, 256, 0, stream>>>(feat, boxes, perm, out);
}